// Round 19
// baseline (459.707 us; speedup 1.0000x reference)
//
#include <hip/hip_runtime.h>

#define NN 50000
#define NE 1600000
#define NB 391        // coarse buckets of 128 nodes (gapped edata layout retained)
#define CAP 4992      // per-bucket capacity: mean 4096 + 8 sigma + pad-to-4
#define NGS 2048      // grid-stride blocks for the edge passes

typedef short bf16x8 __attribute__((ext_vector_type(8)));
typedef float f32x4 __attribute__((ext_vector_type(4)));

static __device__ __forceinline__ unsigned f2bf(float f) {
    union { float f; unsigned u; } v; v.f = f;
    return (v.u + 0x7FFF + ((v.u >> 16) & 1)) >> 16;   // RNE
}

// Accumulate 8 bf16 feats (packed in uint4) * coef into acc[8].
static __device__ __forceinline__ void acc8(float* acc, uint4 h, float c) {
    const unsigned* u = (const unsigned*)&h;
    #pragma unroll
    for (int q = 0; q < 4; ++q) {
        acc[2*q]   += __uint_as_float(u[q] << 16) * c;
        acc[2*q+1] += __uint_as_float(u[q] & 0xFFFF0000u) * c;
    }
}

// Accumulate 8 uint8 feats (biased by +128) * c into acc[8]; cs tracks sum of
// c for the -128 correction.
static __device__ __forceinline__ void accq(float* acc, float& cs, uint2 g, float c) {
    cs += c;
    acc[0] += (float)(g.x & 0xffu) * c;
    acc[1] += (float)((g.x >> 8) & 0xffu) * c;
    acc[2] += (float)((g.x >> 16) & 0xffu) * c;
    acc[3] += (float)(g.x >> 24) * c;
    acc[4] += (float)(g.y & 0xffu) * c;
    acc[5] += (float)((g.y >> 8) & 0xffu) * c;
    acc[6] += (float)((g.y >> 16) & 0xffu) * c;
    acc[7] += (float)(g.y >> 24) * c;
}

// Pass A: per-node edge count + weighted in-degree via global atomics.
// cnt/deg are 200 KB each -> L2-resident; 50K addresses -> low contention.
__global__ __launch_bounds__(256) void build_deg(const int* __restrict__ dst,
        const float* __restrict__ ew, int* __restrict__ cnt,
        float* __restrict__ deg) {
    for (int i = blockIdx.x * 256 + threadIdx.x; i < NE; i += NGS * 256) {
        int d = dst[i];
        atomicAdd(&cnt[d], 1);
        atomicAdd(&deg[d], ew[i]);
    }
}

// Pass B: per-bucket scan of PADDED counts -> rowptr2 {beg,end}, dinv, and
// per-node scatter cursor (ncur, reusing the cnt array). Blocks NB..NB+31
// transpose W1/W2 to bf16 (+ p-order W2/b1 for the int8 feature layout).
__global__ __launch_bounds__(256) void scan_build(int* __restrict__ ncur,
        const float* __restrict__ deg, float* __restrict__ dinv,
        int2* __restrict__ rowptr2,
        const float* __restrict__ W1, const float* __restrict__ W2,
        const float* __restrict__ b1,
        ushort* __restrict__ Wt1, ushort* __restrict__ Wt2,
        float* __restrict__ b1p) {
    int bk = blockIdx.x;
    int t = threadIdx.x;
    if (bk >= NB) {
        for (int idx = (bk - NB) * 256 + t; idx < 41088; idx += 32 * 256) {
            if (idx < 32768) {
                int k = idx >> 7, n = idx & 127;
                Wt1[n * 256 + k] = (ushort)f2bf(W1[idx]);
            } else if (idx < 40960) {
                int i = idx - 32768;
                int k = i >> 6, n = i & 63;
                int kp = ((k & 15) << 3) | (k >> 4);      // p-order: p = m*8 + t
                Wt2[n * 128 + kp] = (ushort)f2bf(W2[i]);
            } else {
                int k = idx - 40960;                       // 0..127
                b1p[((k & 15) << 3) | (k >> 4)] = b1[k];
            }
        }
        return;
    }
    __shared__ int sd[128];
    int node = bk * 128 + t;
    int c = 0;
    if (t < 128 && node < NN) c = ncur[node];
    int cp = (c + 3) & ~3;                 // pad to multiple of 4
    if (t < 128) sd[t] = cp;
    __syncthreads();
    for (int off = 1; off < 128; off <<= 1) {
        int v = 0;
        if (t < 128 && t >= off) v = sd[t - off];
        __syncthreads();
        if (t < 128) sd[t] += v;
        __syncthreads();
    }
    if (t < 128 && node < NN) {
        int loff = sd[t] - cp;
        int beg = bk * CAP + loff;
        rowptr2[node] = make_int2(beg, beg + cp);
        dinv[node] = rsqrtf(deg[node] + 1.0f);
        ncur[node] = beg;                  // cnt array becomes the cursor
    }
}

// Pass C: direct placement — one atomic bump per edge, final 4B edata word
// written in place. Pad slots stay 0 from the upfront memset.
__global__ __launch_bounds__(256) void scatter_edges(const int* __restrict__ src,
        const int* __restrict__ dst, const float* __restrict__ ew,
        int* __restrict__ ncur, unsigned* __restrict__ edata) {
    for (int i = blockIdx.x * 256 + threadIdx.x; i < NE; i += NGS * 256) {
        int d = dst[i];
        int pos = atomicAdd(&ncur[d], 1);
        edata[pos] = (unsigned)src[i] | (f2bf(ew[i]) << 16);
    }
}

// Layer-1 GEMM + int8 row quantization (R5 version, fp32 A with in-loop repack).
// H1q[row][p] (p = m*8+t lane-contiguous order), sscale[row] = rowmax/127,
// stored value u = rint(v/s) + 128 (unsigned, bias 128).
__global__ __launch_bounds__(256) void gemm1_kernel(const float* __restrict__ A,
        const ushort* __restrict__ Bt, unsigned char* __restrict__ H1q,
        float* __restrict__ sscale, const float* __restrict__ dinv, int M) {
    const int K = 256;
    __shared__ __align__(16) ushort As[64][72];
    __shared__ __align__(16) ushort Bs[128][72];
    int tid = threadIdx.x;
    int bm = blockIdx.x * 64;
    int w = tid >> 6, lane = tid & 63;
    int m = lane & 15, quad = lane >> 4;
    f32x4 acc[8] = {};
    int ra = tid >> 2, ksa = (tid & 3) * 16;        // A staging: 64 rows x 64 k
    int rb = tid >> 1, ksb = (tid & 1) * 32;        // B staging: 128 rows x 64 k
    int grow = bm + ra; if (grow >= M) grow = M - 1;
    const float* ap = A + (size_t)grow * K + ksa;
    const ushort* bp = Bt + (size_t)rb * K + ksb;
    for (int k0 = 0; k0 < K; k0 += 64) {
        float4 f0 = *(const float4*)(ap + k0);
        float4 f1 = *(const float4*)(ap + k0 + 4);
        float4 f2 = *(const float4*)(ap + k0 + 8);
        float4 f3 = *(const float4*)(ap + k0 + 12);
        uint4 bv0 = *(const uint4*)(bp + k0);
        uint4 bv1 = *(const uint4*)(bp + k0 + 8);
        uint4 bv2 = *(const uint4*)(bp + k0 + 16);
        uint4 bv3 = *(const uint4*)(bp + k0 + 24);
        uint4 pa, pb;
        pa.x = f2bf(f0.x) | (f2bf(f0.y) << 16);
        pa.y = f2bf(f0.z) | (f2bf(f0.w) << 16);
        pa.z = f2bf(f1.x) | (f2bf(f1.y) << 16);
        pa.w = f2bf(f1.z) | (f2bf(f1.w) << 16);
        pb.x = f2bf(f2.x) | (f2bf(f2.y) << 16);
        pb.y = f2bf(f2.z) | (f2bf(f2.w) << 16);
        pb.z = f2bf(f3.x) | (f2bf(f3.y) << 16);
        pb.w = f2bf(f3.z) | (f2bf(f3.w) << 16);
        __syncthreads();
        *(uint4*)&As[ra][ksa] = pa;
        *(uint4*)&As[ra][ksa + 8] = pb;
        *(uint4*)&Bs[rb][ksb] = bv0;
        *(uint4*)&Bs[rb][ksb + 8] = bv1;
        *(uint4*)&Bs[rb][ksb + 16] = bv2;
        *(uint4*)&Bs[rb][ksb + 24] = bv3;
        __syncthreads();
        #pragma unroll
        for (int ks = 0; ks < 2; ++ks) {
            bf16x8 a = *(const bf16x8*)&As[w * 16 + m][ks * 32 + quad * 8];
            #pragma unroll
            for (int t = 0; t < 8; ++t) {
                bf16x8 b = *(const bf16x8*)&Bs[t * 16 + m][ks * 32 + quad * 8];
                acc[t] = __builtin_amdgcn_mfma_f32_16x16x32_bf16(a, b, acc[t], 0, 0, 0);
            }
        }
    }
    int rbase = bm + w * 16 + quad * 4;
    float dv[4];
    #pragma unroll
    for (int rg = 0; rg < 4; ++rg)
        dv[rg] = (rbase + rg < M) ? dinv[rbase + rg] : 0.0f;
    #pragma unroll
    for (int rg = 0; rg < 4; ++rg) {
        float val[8];
        float mx = 0.0f;
        #pragma unroll
        for (int t = 0; t < 8; ++t) {
            val[t] = dv[rg] * acc[t][rg];
            mx = fmaxf(mx, fabsf(val[t]));
        }
        #pragma unroll
        for (int off = 1; off < 16; off <<= 1)       // row-max across 16 m-lanes
            mx = fmaxf(mx, __shfl_xor(mx, off));
        float s = mx * (1.0f / 127.0f);
        float inv = (mx > 0.0f) ? 127.0f / mx : 0.0f;
        unsigned d0 = 0, d1 = 0;
        #pragma unroll
        for (int t = 0; t < 4; ++t) {
            unsigned q0 = (unsigned)(__float2int_rn(val[t] * inv) + 128);
            unsigned q1 = (unsigned)(__float2int_rn(val[t + 4] * inv) + 128);
            d0 |= (q0 & 255u) << (8 * t);
            d1 |= (q1 & 255u) << (8 * t);
        }
        int row = rbase + rg;
        if (row < M) {
            *(uint2*)&H1q[(size_t)row * 128 + m * 8] = make_uint2(d0, d1);
            if (m == 0) sscale[row] = s;
        }
    }
}

// Fold src row-scale into the edge coefficient: edata1 = {src | bf16(w*s_src)}.
// Padding entries (0) stay 0.  sscale is 200 KB -> L2-resident gathers.
__global__ __launch_bounds__(256) void fix_edata(const unsigned* __restrict__ edata,
        const float* __restrict__ sscale, unsigned* __restrict__ edata1, int total) {
    int i = blockIdx.x * 256 + threadIdx.x;
    if (i >= total) return;
    unsigned e = edata[i];
    float w = __uint_as_float(e & 0xFFFF0000u);
    float c = w * sscale[e & 0xFFFF];
    edata1[i] = (e & 0xFFFFu) | (f2bf(c) << 16);
}

// Fused layer-1 aggregation (int8 gather) + layer-2 GEMM -> bf16 H2.
__global__ __launch_bounds__(256) void agg1_fused_kernel(
        const int2* __restrict__ rowptr2, const unsigned* __restrict__ edata1,
        const unsigned char* __restrict__ Hq, const float* __restrict__ sscale,
        const float* __restrict__ dinv, const float* __restrict__ b1p,
        const ushort* __restrict__ Wt2, ushort* __restrict__ H2) {
    __shared__ __align__(16) ushort Ats[16][136];   // 16 nodes x 128 feat (p-order)
    int tid = threadIdx.x;
    int nl = tid >> 4;                  // node-local 0..15
    int node = blockIdx.x * 16 + nl;    // 3125*16 == NN exactly, no guard
    int glane = tid & 15;
    int2 rp = rowptr2[node];
    int beg = rp.x, end = rp.y;         // end-beg is a multiple of 4
    float acc[8] = {};
    float cs = 0.0f;
    const unsigned char* Hql = Hq + glane * 8;
    int e = beg;
    int n8 = beg + ((end - beg) & ~7);
    for (; e < n8; e += 8) {
        uint4 ma = *(const uint4*)&edata1[e];
        uint4 mb = *(const uint4*)&edata1[e + 4];
        uint2 g0 = *(const uint2*)(Hql + (size_t)(ma.x & 0xFFFF) * 128);
        uint2 g1 = *(const uint2*)(Hql + (size_t)(ma.y & 0xFFFF) * 128);
        uint2 g2 = *(const uint2*)(Hql + (size_t)(ma.z & 0xFFFF) * 128);
        uint2 g3 = *(const uint2*)(Hql + (size_t)(ma.w & 0xFFFF) * 128);
        uint2 g4 = *(const uint2*)(Hql + (size_t)(mb.x & 0xFFFF) * 128);
        uint2 g5 = *(const uint2*)(Hql + (size_t)(mb.y & 0xFFFF) * 128);
        uint2 g6 = *(const uint2*)(Hql + (size_t)(mb.z & 0xFFFF) * 128);
        uint2 g7 = *(const uint2*)(Hql + (size_t)(mb.w & 0xFFFF) * 128);
        accq(acc, cs, g0, __uint_as_float(ma.x & 0xFFFF0000u));
        accq(acc, cs, g1, __uint_as_float(ma.y & 0xFFFF0000u));
        accq(acc, cs, g2, __uint_as_float(ma.z & 0xFFFF0000u));
        accq(acc, cs, g3, __uint_as_float(ma.w & 0xFFFF0000u));
        accq(acc, cs, g4, __uint_as_float(mb.x & 0xFFFF0000u));
        accq(acc, cs, g5, __uint_as_float(mb.y & 0xFFFF0000u));
        accq(acc, cs, g6, __uint_as_float(mb.z & 0xFFFF0000u));
        accq(acc, cs, g7, __uint_as_float(mb.w & 0xFFFF0000u));
    }
    if (e < end) {                      // exactly 4 edges remain
        uint4 ma = *(const uint4*)&edata1[e];
        uint2 g0 = *(const uint2*)(Hql + (size_t)(ma.x & 0xFFFF) * 128);
        uint2 g1 = *(const uint2*)(Hql + (size_t)(ma.y & 0xFFFF) * 128);
        uint2 g2 = *(const uint2*)(Hql + (size_t)(ma.z & 0xFFFF) * 128);
        uint2 g3 = *(const uint2*)(Hql + (size_t)(ma.w & 0xFFFF) * 128);
        accq(acc, cs, g0, __uint_as_float(ma.x & 0xFFFF0000u));
        accq(acc, cs, g1, __uint_as_float(ma.y & 0xFFFF0000u));
        accq(acc, cs, g2, __uint_as_float(ma.z & 0xFFFF0000u));
        accq(acc, cs, g3, __uint_as_float(ma.w & 0xFFFF0000u));
    }
    // self loop (weight 1): coef = sscale[node]
    {
        float ss = sscale[node];
        uint2 gs = *(const uint2*)(Hql + (size_t)node * 128);
        accq(acc, cs, gs, ss);
    }
    float di = dinv[node];
    float corr = -128.0f * cs;
    float4 bv0 = *(const float4*)(b1p + glane * 8);
    float4 bv1 = *(const float4*)(b1p + glane * 8 + 4);
    float v[8];
    #pragma unroll
    for (int j = 0; j < 8; ++j) v[j] = di * (acc[j] + corr);
    v[0] += bv0.x; v[1] += bv0.y; v[2] += bv0.z; v[3] += bv0.w;
    v[4] += bv1.x; v[5] += bv1.y; v[6] += bv1.z; v[7] += bv1.w;
    #pragma unroll
    for (int k = 0; k < 8; ++k) v[k] = fmaxf(v[k], 0.0f);   // relu
    uint4 o;
    o.x = f2bf(v[0]) | (f2bf(v[1]) << 16);
    o.y = f2bf(v[2]) | (f2bf(v[3]) << 16);
    o.z = f2bf(v[4]) | (f2bf(v[5]) << 16);
    o.w = f2bf(v[6]) | (f2bf(v[7]) << 16);
    *(uint4*)&Ats[nl][glane * 8] = o;
    __syncthreads();
    // MFMA: wave w -> cols [w*16, w*16+16); A = Ats (16 nodes x K=128, p-order)
    int w = tid >> 6, lane = tid & 63;
    int m = lane & 15, quad = lane >> 4;
    const ushort* bp = Wt2 + (size_t)(w * 16 + m) * 128 + quad * 8;
    f32x4 c2 = {};
    #pragma unroll
    for (int kc = 0; kc < 4; ++kc) {
        bf16x8 a = *(const bf16x8*)&Ats[m][kc * 32 + quad * 8];
        bf16x8 b = *(const bf16x8*)(bp + kc * 32);
        c2 = __builtin_amdgcn_mfma_f32_16x16x32_bf16(a, b, c2, 0, 0, 0);
    }
    int rbase = blockIdx.x * 16 + quad * 4;
    #pragma unroll
    for (int rg = 0; rg < 4; ++rg) {
        float dvr = dinv[rbase + rg];
        H2[(size_t)(rbase + rg) * 64 + w * 16 + m] = (ushort)f2bf(dvr * c2[rg]);
    }
}

// Layer-2 aggregation: 8 lanes/node over H2[NN][64] (bf16) -> out fp32.
__global__ __launch_bounds__(256) void agg2_kernel(
        const int2* __restrict__ rowptr2, const unsigned* __restrict__ edata,
        const ushort* __restrict__ H, const float* __restrict__ dinv,
        const float* __restrict__ bias, float* __restrict__ out) {
    int node = blockIdx.x * 32 + (threadIdx.x >> 3);
    if (node >= NN) return;
    int glane = threadIdx.x & 7;
    int2 rp = rowptr2[node];
    int beg = rp.x, end = rp.y;
    float acc[8] = {};
    const ushort* Hl = H + (size_t)glane * 8;
    int e = beg;
    int n8 = beg + ((end - beg) & ~7);
    for (; e < n8; e += 8) {
        uint4 ma = *(const uint4*)&edata[e];
        uint4 mb = *(const uint4*)&edata[e + 4];
        uint4 h0 = *(const uint4*)(Hl + (size_t)(ma.x & 0xFFFF) * 64);
        uint4 h1 = *(const uint4*)(Hl + (size_t)(ma.y & 0xFFFF) * 64);
        uint4 h2 = *(const uint4*)(Hl + (size_t)(ma.z & 0xFFFF) * 64);
        uint4 h3 = *(const uint4*)(Hl + (size_t)(ma.w & 0xFFFF) * 64);
        uint4 h4 = *(const uint4*)(Hl + (size_t)(mb.x & 0xFFFF) * 64);
        uint4 h5 = *(const uint4*)(Hl + (size_t)(mb.y & 0xFFFF) * 64);
        uint4 h6 = *(const uint4*)(Hl + (size_t)(mb.z & 0xFFFF) * 64);
        uint4 h7 = *(const uint4*)(Hl + (size_t)(mb.w & 0xFFFF) * 64);
        acc8(acc, h0, __uint_as_float(ma.x & 0xFFFF0000u));
        acc8(acc, h1, __uint_as_float(ma.y & 0xFFFF0000u));
        acc8(acc, h2, __uint_as_float(ma.z & 0xFFFF0000u));
        acc8(acc, h3, __uint_as_float(ma.w & 0xFFFF0000u));
        acc8(acc, h4, __uint_as_float(mb.x & 0xFFFF0000u));
        acc8(acc, h5, __uint_as_float(mb.y & 0xFFFF0000u));
        acc8(acc, h6, __uint_as_float(mb.z & 0xFFFF0000u));
        acc8(acc, h7, __uint_as_float(mb.w & 0xFFFF0000u));
    }
    if (e < end) {                      // exactly 4 edges remain
        uint4 ma = *(const uint4*)&edata[e];
        uint4 h0 = *(const uint4*)(Hl + (size_t)(ma.x & 0xFFFF) * 64);
        uint4 h1 = *(const uint4*)(Hl + (size_t)(ma.y & 0xFFFF) * 64);
        uint4 h2 = *(const uint4*)(Hl + (size_t)(ma.z & 0xFFFF) * 64);
        uint4 h3 = *(const uint4*)(Hl + (size_t)(ma.w & 0xFFFF) * 64);
        acc8(acc, h0, __uint_as_float(ma.x & 0xFFFF0000u));
        acc8(acc, h1, __uint_as_float(ma.y & 0xFFFF0000u));
        acc8(acc, h2, __uint_as_float(ma.z & 0xFFFF0000u));
        acc8(acc, h3, __uint_as_float(ma.w & 0xFFFF0000u));
    }
    float di = dinv[node];
    uint4 hn = *(const uint4*)(Hl + (size_t)node * 64);
    const unsigned* un = (const unsigned*)&hn;
    float4 bv0 = *(const float4*)(bias + glane * 8);
    float4 bv1 = *(const float4*)(bias + glane * 8 + 4);
    float v[8];
    #pragma unroll
    for (int q = 0; q < 4; ++q) {
        v[2*q]   = di * (acc[2*q]   + __uint_as_float(un[q] << 16));
        v[2*q+1] = di * (acc[2*q+1] + __uint_as_float(un[q] & 0xFFFF0000u));
    }
    v[0] += bv0.x; v[1] += bv0.y; v[2] += bv0.z; v[3] += bv0.w;
    v[4] += bv1.x; v[5] += bv1.y; v[6] += bv1.z; v[7] += bv1.w;
    float* o = out + (size_t)node * 64 + glane * 8;
    *(float4*)(o)     = make_float4(v[0], v[1], v[2], v[3]);
    *(float4*)(o + 4) = make_float4(v[4], v[5], v[6], v[7]);
}

extern "C" void kernel_launch(void* const* d_in, const int* in_sizes, int n_in,
                              void* d_out, int out_size, void* d_ws, size_t ws_size,
                              hipStream_t stream) {
    const float* x  = (const float*)d_in[0];
    const int*   ei = (const int*)d_in[1];
    const float* ew = (const float*)d_in[2];
    const float* W1 = (const float*)d_in[3];
    const float* b1 = (const float*)d_in[4];
    const float* W2 = (const float*)d_in[5];
    const float* b2 = (const float*)d_in[6];
    const int* src = ei;
    const int* dst = ei + NE;
    float* out = (float*)d_out;

    // workspace (dword offsets) — no ebuf:
    float*  ws      = (float*)d_ws;
    float*  dinv    = ws;                          // 50048 dw
    int2*   rowptr2 = (int2*)(ws + 50048);         // 100096 dw (NN int2)
    int*    cnt     = (int*)(ws + 150144);         // 50048 dw (becomes ncur)
    float*  deg     = ws + 200192;                 // 50048 dw (adjacent to cnt)
    ushort* Wt1     = (ushort*)(ws + 250240);      // 16384 dw
    ushort* Wt2     = (ushort*)(ws + 266624);      // 4096 dw
    float*  b1p     = ws + 270720;                 // 128 dw
    float*  sscale  = ws + 270848;                 // 50048 dw -> ends 320896
    unsigned* edata = (unsigned*)(ws + 320896);    // 391*CAP = 1,951,872 dw
    unsigned* edata1= (unsigned*)(ws + 2272768);   // 1,951,872 dw
    unsigned char* H1q = (unsigned char*)(ws + 4224640);  // [NN][128] u8 = 1.6M dw
    ushort* H2      = (ushort*)(ws + 5824640);     // [NN][64] bf16 = 1.6M dw
    // total 7,424,640 dw = 29.7 MB

    // zero cnt+deg (adjacent, one call) and edata (pad slots must read 0)
    hipMemsetAsync(cnt, 0, 2 * 50048 * sizeof(int), stream);
    hipMemsetAsync(edata, 0, (size_t)NB * CAP * sizeof(unsigned), stream);
    // Pass A: per-node count + weighted degree (global atomics)
    build_deg<<<NGS, 256, 0, stream>>>(dst, ew, cnt, deg);
    // Pass B: per-bucket scan -> rowptr2/dinv/cursors; spare blocks transpose W
    scan_build<<<NB + 32, 256, 0, stream>>>(cnt, deg, dinv, rowptr2,
                                            W1, W2, b1, Wt1, Wt2, b1p);
    // Pass C: direct edge placement (atomic bump per edge)
    scatter_edges<<<NGS, 256, 0, stream>>>(src, dst, ew, cnt, edata);

    // Layer 1: H1q(int8,p-order) + sscale = quant(dinv*(x @ W1))
    gemm1_kernel<<<782, 256, 0, stream>>>(x, Wt1, H1q, sscale, dinv, NN);
    // Fold s_src into edge coefficients for the int8 gather
    fix_edata<<<(NB * CAP + 255) / 256, 256, 0, stream>>>(edata, sscale, edata1,
                                                          NB * CAP);
    // Fused: agg(int8 H1) -> relu -> @W2 -> dinv -> H2 (bf16)
    agg1_fused_kernel<<<3125, 256, 0, stream>>>(rowptr2, edata1, H1q, sscale,
                                                dinv, b1p, Wt2, H2);
    // Layer 2 aggregation (bf16) -> out(fp32)
    agg2_kernel<<<1563, 256, 0, stream>>>(rowptr2, edata, H2, dinv, b2, out);
}

// Round 21
// 226.459 us; speedup vs baseline: 2.0300x; 2.0300x over previous
//
#include <hip/hip_runtime.h>

#define NN 50000
#define NE 1600000
#define NB 391        // coarse buckets of 128 nodes
#define NBLK 512      // scatter blocks (3125 edges each)
#define EPB 3125      // edges per scatter block
#define CAP 4992      // per-bucket capacity: mean 4096 + 8 sigma (512) + pad-to-4 (<=384)

typedef short bf16x8 __attribute__((ext_vector_type(8)));
typedef float f32x4 __attribute__((ext_vector_type(4)));

static __device__ __forceinline__ unsigned f2bf(float f) {
    union { float f; unsigned u; } v; v.f = f;
    return (v.u + 0x7FFF + ((v.u >> 16) & 1)) >> 16;   // RNE
}

// Accumulate 8 bf16 feats (packed in uint4) * coef into acc[8].
static __device__ __forceinline__ void acc8(float* acc, uint4 h, float c) {
    const unsigned* u = (const unsigned*)&h;
    #pragma unroll
    for (int q = 0; q < 4; ++q) {
        acc[2*q]   += __uint_as_float(u[q] << 16) * c;
        acc[2*q+1] += __uint_as_float(u[q] & 0xFFFF0000u) * c;
    }
}

// Accumulate 8 uint8 feats (biased by +128) * c into acc[8]; cs tracks sum of
// c for the -128 correction.
static __device__ __forceinline__ void accq(float* acc, float& cs, uint2 g, float c) {
    cs += c;
    acc[0] += (float)(g.x & 0xffu) * c;
    acc[1] += (float)((g.x >> 8) & 0xffu) * c;
    acc[2] += (float)((g.x >> 16) & 0xffu) * c;
    acc[3] += (float)(g.x >> 24) * c;
    acc[4] += (float)(g.y & 0xffu) * c;
    acc[5] += (float)((g.y >> 8) & 0xffu) * c;
    acc[6] += (float)((g.y >> 16) & 0xffu) * c;
    acc[7] += (float)(g.y >> 24) * c;
}

// K1: fused histogram + range-reserve + bucket scatter (blocks 0..511);
// blocks 512..543 transpose W1/W2 to bf16 (+ permuted W2/b1 for the int8
// p-order feature layout). dst staged in LDS (read once).
__global__ __launch_bounds__(256) void k1_scatter(const int* __restrict__ src,
        const int* __restrict__ dst, const float* __restrict__ ew,
        int* __restrict__ cursor, int2* __restrict__ ebuf,
        const float* __restrict__ W1, const float* __restrict__ W2,
        const float* __restrict__ b1,
        ushort* __restrict__ Wt1, ushort* __restrict__ Wt2,
        float* __restrict__ b1p) {
    int blk = blockIdx.x;
    int t = threadIdx.x;
    if (blk >= NBLK) {
        for (int idx = (blk - NBLK) * 256 + t; idx < 41088; idx += 32 * 256) {
            if (idx < 32768) {
                int k = idx >> 7, n = idx & 127;
                Wt1[n * 256 + k] = (ushort)f2bf(W1[idx]);
            } else if (idx < 40960) {
                int i = idx - 32768;
                int k = i >> 6, n = i & 63;
                int kp = ((k & 15) << 3) | (k >> 4);      // p-order: p = m*8 + t
                Wt2[n * 128 + kp] = (ushort)f2bf(W2[i]);
            } else {
                int k = idx - 40960;                       // 0..127
                b1p[((k & 15) << 3) | (k >> 4)] = b1[k];
            }
        }
        return;
    }
    __shared__ int h[NB];
    __shared__ int curs[NB];
    __shared__ int sdst[EPB];         // 12.5 KB: dst chunk staged, read global once
    for (int i = t; i < NB; i += 256) h[i] = 0;
    __syncthreads();
    int base = blk * EPB;
    for (int k = t; k < EPB; k += 256) {
        int d = dst[base + k];
        sdst[k] = d;
        atomicAdd(&h[d >> 7], 1);
    }
    __syncthreads();
    for (int i = t; i < NB; i += 256)
        curs[i] = i * CAP + atomicAdd(&cursor[i], h[i]);   // reserve range
    __syncthreads();
    for (int k = t; k < EPB; k += 256) {
        int d = sdst[k];
        int s = src[base + k];
        float w = ew[base + k];
        int pos = atomicAdd(&curs[d >> 7], 1);
        ebuf[pos] = make_int2(s | ((d & 127) << 16), __float_as_int(w));
    }
}

// P4: one block (512 thr) per bucket — LDS-staged count + scan + place.
// DETERMINISM HARDENING (R20 post-mortem): the fp32 LDS atomicAdd degree sum
// was the one place atomic ORDER changed computed VALUES (deg -> dinv ->
// int8 quantization boundaries). Now: placement stages fp32 w per slot in
// sw[], and each node's owner thread sums its contiguous range sequentially
// in DOUBLE (exact for these magnitudes -> order-independent).
__global__ __launch_bounds__(512) void p4_build(const int2* __restrict__ ebuf,
        const int* __restrict__ cursor, unsigned* __restrict__ edata,
        float* __restrict__ dinv, int2* __restrict__ rowptr2) {
    __shared__ int cnt[128], loff[128], cur[128], sd[128];
    __shared__ int2 se[CAP];          // 39.9 KB bucket staging
    __shared__ float sw[CAP];         // 20.0 KB fp32 weights per placed slot
    int bk = blockIdx.x;
    int t = threadIdx.x;
    int ebase = bk * CAP;
    int ecnt = cursor[bk];
    if (ecnt > CAP) ecnt = CAP;       // unreachable for this input; OOB guard
    if (t < 128) { cnt[t] = 0; cur[t] = 0; }
    __syncthreads();
    for (int i = t; i < ecnt; i += 512) {
        int2 e = ebuf[ebase + i];
        se[i] = e;
        int dl = (e.x >> 16) & 127;
        atomicAdd(&cnt[dl], 1);       // int atomics: order-independent
    }
    __syncthreads();
    if (t < 128) sd[t] = (cnt[t] + 3) & ~3;   // scan PADDED counts
    __syncthreads();
    for (int off = 1; off < 128; off <<= 1) {
        int v = 0;
        if (t < 128 && t >= off) v = sd[t - off];
        __syncthreads();
        if (t < 128) sd[t] += v;
        __syncthreads();
    }
    if (t < 128) {
        int cp = (cnt[t] + 3) & ~3;
        loff[t] = sd[t] - cp;
    }
    __syncthreads();
    int node = bk * 128 + t;
    if (t < 128 && node < NN) {
        int cp = (cnt[t] + 3) & ~3;
        int beg = ebase + loff[t];
        rowptr2[node] = make_int2(beg, beg + cp);
        for (int i = cnt[t]; i < cp; ++i)      // zero-coef padding
            edata[ebase + loff[t] + i] = 0;
    }
    for (int i = t; i < ecnt; i += 512) {
        int2 e = se[i];
        int dl = (e.x >> 16) & 127;
        int slot = loff[dl] + atomicAdd(&cur[dl], 1);
        float w = __int_as_float(e.y);
        edata[ebase + slot] = (unsigned)(e.x & 0xFFFF) | (f2bf(w) << 16);
        sw[slot] = w;
    }
    __syncthreads();
    // deterministic degree: sequential double sum over own contiguous range
    if (t < 128 && node < NN) {
        double s = 0.0;
        int b = loff[t], c = cnt[t];
        for (int i = 0; i < c; ++i) s += (double)sw[b + i];
        dinv[node] = rsqrtf((float)s + 1.0f);
    }
}

// Layer-1 GEMM + int8 row quantization.
// H1q[row][p] (p = m*8+t lane-contiguous order), sscale[row] = rowmax/127,
// stored value u = rint(v/s) + 128 (unsigned, bias 128).
__global__ __launch_bounds__(256) void gemm1_kernel(const float* __restrict__ A,
        const ushort* __restrict__ Bt, unsigned char* __restrict__ H1q,
        float* __restrict__ sscale, const float* __restrict__ dinv, int M) {
    const int K = 256;
    __shared__ __align__(16) ushort As[64][72];
    __shared__ __align__(16) ushort Bs[128][72];
    int tid = threadIdx.x;
    int bm = blockIdx.x * 64;
    int w = tid >> 6, lane = tid & 63;
    int m = lane & 15, quad = lane >> 4;
    f32x4 acc[8] = {};
    int ra = tid >> 2, ksa = (tid & 3) * 16;        // A staging: 64 rows x 64 k
    int rb = tid >> 1, ksb = (tid & 1) * 32;        // B staging: 128 rows x 64 k
    int grow = bm + ra; if (grow >= M) grow = M - 1;
    const float* ap = A + (size_t)grow * K + ksa;
    const ushort* bp = Bt + (size_t)rb * K + ksb;
    for (int k0 = 0; k0 < K; k0 += 64) {
        float4 f0 = *(const float4*)(ap + k0);
        float4 f1 = *(const float4*)(ap + k0 + 4);
        float4 f2 = *(const float4*)(ap + k0 + 8);
        float4 f3 = *(const float4*)(ap + k0 + 12);
        uint4 bv0 = *(const uint4*)(bp + k0);
        uint4 bv1 = *(const uint4*)(bp + k0 + 8);
        uint4 bv2 = *(const uint4*)(bp + k0 + 16);
        uint4 bv3 = *(const uint4*)(bp + k0 + 24);
        uint4 pa, pb;
        pa.x = f2bf(f0.x) | (f2bf(f0.y) << 16);
        pa.y = f2bf(f0.z) | (f2bf(f0.w) << 16);
        pa.z = f2bf(f1.x) | (f2bf(f1.y) << 16);
        pa.w = f2bf(f1.z) | (f2bf(f1.w) << 16);
        pb.x = f2bf(f2.x) | (f2bf(f2.y) << 16);
        pb.y = f2bf(f2.z) | (f2bf(f2.w) << 16);
        pb.z = f2bf(f3.x) | (f2bf(f3.y) << 16);
        pb.w = f2bf(f3.z) | (f2bf(f3.w) << 16);
        __syncthreads();
        *(uint4*)&As[ra][ksa] = pa;
        *(uint4*)&As[ra][ksa + 8] = pb;
        *(uint4*)&Bs[rb][ksb] = bv0;
        *(uint4*)&Bs[rb][ksb + 8] = bv1;
        *(uint4*)&Bs[rb][ksb + 16] = bv2;
        *(uint4*)&Bs[rb][ksb + 24] = bv3;
        __syncthreads();
        #pragma unroll
        for (int ks = 0; ks < 2; ++ks) {
            bf16x8 a = *(const bf16x8*)&As[w * 16 + m][ks * 32 + quad * 8];
            #pragma unroll
            for (int t = 0; t < 8; ++t) {
                bf16x8 b = *(const bf16x8*)&Bs[t * 16 + m][ks * 32 + quad * 8];
                acc[t] = __builtin_amdgcn_mfma_f32_16x16x32_bf16(a, b, acc[t], 0, 0, 0);
            }
        }
    }
    int rbase = bm + w * 16 + quad * 4;
    float dv[4];
    #pragma unroll
    for (int rg = 0; rg < 4; ++rg)
        dv[rg] = (rbase + rg < M) ? dinv[rbase + rg] : 0.0f;
    #pragma unroll
    for (int rg = 0; rg < 4; ++rg) {
        float val[8];
        float mx = 0.0f;
        #pragma unroll
        for (int t = 0; t < 8; ++t) {
            val[t] = dv[rg] * acc[t][rg];
            mx = fmaxf(mx, fabsf(val[t]));
        }
        #pragma unroll
        for (int off = 1; off < 16; off <<= 1)       // row-max across 16 m-lanes
            mx = fmaxf(mx, __shfl_xor(mx, off));
        float s = mx * (1.0f / 127.0f);
        float inv = (mx > 0.0f) ? 127.0f / mx : 0.0f;
        unsigned d0 = 0, d1 = 0;
        #pragma unroll
        for (int t = 0; t < 4; ++t) {
            unsigned q0 = (unsigned)(__float2int_rn(val[t] * inv) + 128);
            unsigned q1 = (unsigned)(__float2int_rn(val[t + 4] * inv) + 128);
            d0 |= (q0 & 255u) << (8 * t);
            d1 |= (q1 & 255u) << (8 * t);
        }
        int row = rbase + rg;
        if (row < M) {
            *(uint2*)&H1q[(size_t)row * 128 + m * 8] = make_uint2(d0, d1);
            if (m == 0) sscale[row] = s;
        }
    }
}

// Fold src row-scale into the edge coefficient: edata1 = {src | bf16(w*s_src)}.
// Padding entries (0) stay 0.  sscale is 200 KB -> L2-resident gathers.
__global__ __launch_bounds__(256) void fix_edata(const unsigned* __restrict__ edata,
        const float* __restrict__ sscale, unsigned* __restrict__ edata1, int total) {
    int i = blockIdx.x * 256 + threadIdx.x;
    if (i >= total) return;
    unsigned e = edata[i];
    float w = __uint_as_float(e & 0xFFFF0000u);
    float c = w * sscale[e & 0xFFFF];
    edata1[i] = (e & 0xFFFFu) | (f2bf(c) << 16);
}

// Fused layer-1 aggregation (int8 gather) + layer-2 GEMM -> bf16 H2.
__global__ __launch_bounds__(256) void agg1_fused_kernel(
        const int2* __restrict__ rowptr2, const unsigned* __restrict__ edata1,
        const unsigned char* __restrict__ Hq, const float* __restrict__ sscale,
        const float* __restrict__ dinv, const float* __restrict__ b1p,
        const ushort* __restrict__ Wt2, ushort* __restrict__ H2) {
    __shared__ __align__(16) ushort Ats[16][136];   // 16 nodes x 128 feat (p-order)
    int tid = threadIdx.x;
    int nl = tid >> 4;                  // node-local 0..15
    int node = blockIdx.x * 16 + nl;    // 3125*16 == NN exactly, no guard
    int glane = tid & 15;
    int2 rp = rowptr2[node];
    int beg = rp.x, end = rp.y;         // end-beg is a multiple of 4
    float acc[8] = {};
    float cs = 0.0f;
    const unsigned char* Hql = Hq + glane * 8;
    int e = beg;
    int n8 = beg + ((end - beg) & ~7);
    for (; e < n8; e += 8) {
        uint4 ma = *(const uint4*)&edata1[e];
        uint4 mb = *(const uint4*)&edata1[e + 4];
        uint2 g0 = *(const uint2*)(Hql + (size_t)(ma.x & 0xFFFF) * 128);
        uint2 g1 = *(const uint2*)(Hql + (size_t)(ma.y & 0xFFFF) * 128);
        uint2 g2 = *(const uint2*)(Hql + (size_t)(ma.z & 0xFFFF) * 128);
        uint2 g3 = *(const uint2*)(Hql + (size_t)(ma.w & 0xFFFF) * 128);
        uint2 g4 = *(const uint2*)(Hql + (size_t)(mb.x & 0xFFFF) * 128);
        uint2 g5 = *(const uint2*)(Hql + (size_t)(mb.y & 0xFFFF) * 128);
        uint2 g6 = *(const uint2*)(Hql + (size_t)(mb.z & 0xFFFF) * 128);
        uint2 g7 = *(const uint2*)(Hql + (size_t)(mb.w & 0xFFFF) * 128);
        accq(acc, cs, g0, __uint_as_float(ma.x & 0xFFFF0000u));
        accq(acc, cs, g1, __uint_as_float(ma.y & 0xFFFF0000u));
        accq(acc, cs, g2, __uint_as_float(ma.z & 0xFFFF0000u));
        accq(acc, cs, g3, __uint_as_float(ma.w & 0xFFFF0000u));
        accq(acc, cs, g4, __uint_as_float(mb.x & 0xFFFF0000u));
        accq(acc, cs, g5, __uint_as_float(mb.y & 0xFFFF0000u));
        accq(acc, cs, g6, __uint_as_float(mb.z & 0xFFFF0000u));
        accq(acc, cs, g7, __uint_as_float(mb.w & 0xFFFF0000u));
    }
    if (e < end) {                      // exactly 4 edges remain
        uint4 ma = *(const uint4*)&edata1[e];
        uint2 g0 = *(const uint2*)(Hql + (size_t)(ma.x & 0xFFFF) * 128);
        uint2 g1 = *(const uint2*)(Hql + (size_t)(ma.y & 0xFFFF) * 128);
        uint2 g2 = *(const uint2*)(Hql + (size_t)(ma.z & 0xFFFF) * 128);
        uint2 g3 = *(const uint2*)(Hql + (size_t)(ma.w & 0xFFFF) * 128);
        accq(acc, cs, g0, __uint_as_float(ma.x & 0xFFFF0000u));
        accq(acc, cs, g1, __uint_as_float(ma.y & 0xFFFF0000u));
        accq(acc, cs, g2, __uint_as_float(ma.z & 0xFFFF0000u));
        accq(acc, cs, g3, __uint_as_float(ma.w & 0xFFFF0000u));
    }
    // self loop (weight 1): coef = sscale[node]
    {
        float ss = sscale[node];
        uint2 gs = *(const uint2*)(Hql + (size_t)node * 128);
        accq(acc, cs, gs, ss);
    }
    float di = dinv[node];
    float corr = -128.0f * cs;
    float4 bv0 = *(const float4*)(b1p + glane * 8);
    float4 bv1 = *(const float4*)(b1p + glane * 8 + 4);
    float v[8];
    #pragma unroll
    for (int j = 0; j < 8; ++j) v[j] = di * (acc[j] + corr);
    v[0] += bv0.x; v[1] += bv0.y; v[2] += bv0.z; v[3] += bv0.w;
    v[4] += bv1.x; v[5] += bv1.y; v[6] += bv1.z; v[7] += bv1.w;
    #pragma unroll
    for (int k = 0; k < 8; ++k) v[k] = fmaxf(v[k], 0.0f);   // relu
    uint4 o;
    o.x = f2bf(v[0]) | (f2bf(v[1]) << 16);
    o.y = f2bf(v[2]) | (f2bf(v[3]) << 16);
    o.z = f2bf(v[4]) | (f2bf(v[5]) << 16);
    o.w = f2bf(v[6]) | (f2bf(v[7]) << 16);
    *(uint4*)&Ats[nl][glane * 8] = o;
    __syncthreads();
    // MFMA: wave w -> cols [w*16, w*16+16); A = Ats (16 nodes x K=128, p-order)
    // Wt2 rows are in matching p-order -> dot products correct.
    int w = tid >> 6, lane = tid & 63;
    int m = lane & 15, quad = lane >> 4;
    const ushort* bp = Wt2 + (size_t)(w * 16 + m) * 128 + quad * 8;
    f32x4 c2 = {};
    #pragma unroll
    for (int kc = 0; kc < 4; ++kc) {
        bf16x8 a = *(const bf16x8*)&Ats[m][kc * 32 + quad * 8];
        bf16x8 b = *(const bf16x8*)(bp + kc * 32);
        c2 = __builtin_amdgcn_mfma_f32_16x16x32_bf16(a, b, c2, 0, 0, 0);
    }
    int rbase = blockIdx.x * 16 + quad * 4;
    #pragma unroll
    for (int rg = 0; rg < 4; ++rg) {
        float dvr = dinv[rbase + rg];
        H2[(size_t)(rbase + rg) * 64 + w * 16 + m] = (ushort)f2bf(dvr * c2[rg]);
    }
}

// Layer-2 aggregation: 8 lanes/node over H2[NN][64] (bf16) -> out fp32.
__global__ __launch_bounds__(256) void agg2_kernel(
        const int2* __restrict__ rowptr2, const unsigned* __restrict__ edata,
        const ushort* __restrict__ H, const float* __restrict__ dinv,
        const float* __restrict__ bias, float* __restrict__ out) {
    int node = blockIdx.x * 32 + (threadIdx.x >> 3);
    if (node >= NN) return;
    int glane = threadIdx.x & 7;
    int2 rp = rowptr2[node];
    int beg = rp.x, end = rp.y;
    float acc[8] = {};
    const ushort* Hl = H + (size_t)glane * 8;
    int e = beg;
    int n8 = beg + ((end - beg) & ~7);
    for (; e < n8; e += 8) {
        uint4 ma = *(const uint4*)&edata[e];
        uint4 mb = *(const uint4*)&edata[e + 4];
        uint4 h0 = *(const uint4*)(Hl + (size_t)(ma.x & 0xFFFF) * 64);
        uint4 h1 = *(const uint4*)(Hl + (size_t)(ma.y & 0xFFFF) * 64);
        uint4 h2 = *(const uint4*)(Hl + (size_t)(ma.z & 0xFFFF) * 64);
        uint4 h3 = *(const uint4*)(Hl + (size_t)(ma.w & 0xFFFF) * 64);
        uint4 h4 = *(const uint4*)(Hl + (size_t)(mb.x & 0xFFFF) * 64);
        uint4 h5 = *(const uint4*)(Hl + (size_t)(mb.y & 0xFFFF) * 64);
        uint4 h6 = *(const uint4*)(Hl + (size_t)(mb.z & 0xFFFF) * 64);
        uint4 h7 = *(const uint4*)(Hl + (size_t)(mb.w & 0xFFFF) * 64);
        acc8(acc, h0, __uint_as_float(ma.x & 0xFFFF0000u));
        acc8(acc, h1, __uint_as_float(ma.y & 0xFFFF0000u));
        acc8(acc, h2, __uint_as_float(ma.z & 0xFFFF0000u));
        acc8(acc, h3, __uint_as_float(ma.w & 0xFFFF0000u));
        acc8(acc, h4, __uint_as_float(mb.x & 0xFFFF0000u));
        acc8(acc, h5, __uint_as_float(mb.y & 0xFFFF0000u));
        acc8(acc, h6, __uint_as_float(mb.z & 0xFFFF0000u));
        acc8(acc, h7, __uint_as_float(mb.w & 0xFFFF0000u));
    }
    if (e < end) {                      // exactly 4 edges remain
        uint4 ma = *(const uint4*)&edata[e];
        uint4 h0 = *(const uint4*)(Hl + (size_t)(ma.x & 0xFFFF) * 64);
        uint4 h1 = *(const uint4*)(Hl + (size_t)(ma.y & 0xFFFF) * 64);
        uint4 h2 = *(const uint4*)(Hl + (size_t)(ma.z & 0xFFFF) * 64);
        uint4 h3 = *(const uint4*)(Hl + (size_t)(ma.w & 0xFFFF) * 64);
        acc8(acc, h0, __uint_as_float(ma.x & 0xFFFF0000u));
        acc8(acc, h1, __uint_as_float(ma.y & 0xFFFF0000u));
        acc8(acc, h2, __uint_as_float(ma.z & 0xFFFF0000u));
        acc8(acc, h3, __uint_as_float(ma.w & 0xFFFF0000u));
    }
    float di = dinv[node];
    uint4 hn = *(const uint4*)(Hl + (size_t)node * 64);
    const unsigned* un = (const unsigned*)&hn;
    float4 bv0 = *(const float4*)(bias + glane * 8);
    float4 bv1 = *(const float4*)(bias + glane * 8 + 4);
    float v[8];
    #pragma unroll
    for (int q = 0; q < 4; ++q) {
        v[2*q]   = di * (acc[2*q]   + __uint_as_float(un[q] << 16));
        v[2*q+1] = di * (acc[2*q+1] + __uint_as_float(un[q] & 0xFFFF0000u));
    }
    v[0] += bv0.x; v[1] += bv0.y; v[2] += bv0.z; v[3] += bv0.w;
    v[4] += bv1.x; v[5] += bv1.y; v[6] += bv1.z; v[7] += bv1.w;
    float* o = out + (size_t)node * 64 + glane * 8;
    *(float4*)(o)     = make_float4(v[0], v[1], v[2], v[3]);
    *(float4*)(o + 4) = make_float4(v[4], v[5], v[6], v[7]);
}

extern "C" void kernel_launch(void* const* d_in, const int* in_sizes, int n_in,
                              void* d_out, int out_size, void* d_ws, size_t ws_size,
                              hipStream_t stream) {
    const float* x  = (const float*)d_in[0];
    const int*   ei = (const int*)d_in[1];
    const float* ew = (const float*)d_in[2];
    const float* W1 = (const float*)d_in[3];
    const float* b1 = (const float*)d_in[4];
    const float* W2 = (const float*)d_in[5];
    const float* b2 = (const float*)d_in[6];
    const int* src = ei;
    const int* dst = ei + NE;
    float* out = (float*)d_out;

    // workspace (dword offsets) — R5 layout:
    float*  ws      = (float*)d_ws;
    float*  dinv    = ws;                          // 50048 dw
    int2*   rowptr2 = (int2*)(ws + 50048);         // 100096 dw (NN int2)
    int*    cursor  = (int*)(ws + 150144);         // 512 dw (391 used)
    ushort* Wt1     = (ushort*)(ws + 150656);      // 16384 dw
    ushort* Wt2     = (ushort*)(ws + 167040);      // 4096 dw
    float*  b1p     = ws + 171136;                 // 128 dw
    float*  sscale  = ws + 171264;                 // 50048 dw -> ends 221312
    unsigned* edata = (unsigned*)(ws + 221312);    // 391*CAP = 1,951,872 dw
    unsigned* edata1= (unsigned*)(ws + 2173184);   // 1,951,872 dw
    unsigned char* H1q = (unsigned char*)(ws + 4125056);  // [NN][128] u8 = 1.6M dw
    ushort* H2      = (ushort*)(ws + 5725056);     // [NN][64] bf16 = 1.6M dw
    int2*   ebuf    = (int2*)edata1;               // aliases edata1+H1q+H2 head
    // (ebuf needs 3,903,744 dw; edata1..H2 span 5.2M dw, all dead during k1/p4)
    // total 7,325,056 dw = 29.3 MB

    hipMemsetAsync(cursor, 0, NB * sizeof(int), stream);
    // Scan-free CSR build: hist + reserve + scatter (1 launch), then sort (1 launch)
    k1_scatter<<<NBLK + 32, 256, 0, stream>>>(src, dst, ew, cursor, ebuf,
                                              W1, W2, b1, Wt1, Wt2, b1p);
    p4_build<<<NB, 512, 0, stream>>>(ebuf, cursor, edata, dinv, rowptr2);

    // Layer 1: H1q(int8,p-order) + sscale = quant(dinv*(x @ W1))
    gemm1_kernel<<<782, 256, 0, stream>>>(x, Wt1, H1q, sscale, dinv, NN);
    // Fold s_src into edge coefficients for the int8 gather
    fix_edata<<<(NB * CAP + 255) / 256, 256, 0, stream>>>(edata, sscale, edata1,
                                                          NB * CAP);
    // Fused: agg(int8 H1) -> relu -> @W2 -> dinv -> H2 (bf16)
    agg1_fused_kernel<<<3125, 256, 0, stream>>>(rowptr2, edata1, H1q, sscale,
                                                dinv, b1p, Wt2, H2);
    // Layer 2 aggregation (bf16) -> out(fp32)
    agg2_kernel<<<1563, 256, 0, stream>>>(rowptr2, edata, H2, dinv, b2, out);
}